// Round 5
// baseline (270.228 us; speedup 1.0000x reference)
//
#include <hip/hip_runtime.h>
#include <hip/hip_bf16.h>
#include <math.h>

#define L_SEQ 512
#define DM 768
#define DI 1536
#define DS 64
#define DC 4
#define DR 48
#define NXD 176  // DR + 2*DS
#define NC 8     // time chunks
#define TC 64    // steps per chunk

typedef __attribute__((ext_vector_type(8))) short short8;
typedef __attribute__((ext_vector_type(4))) float float4v;

// ---------------------------------------------------------------------------
// helpers
// ---------------------------------------------------------------------------
__device__ __forceinline__ float bp_add(float p, int addr) {
  return p + __int_as_float(__builtin_amdgcn_ds_bpermute(addr, __float_as_int(p)));
}
__device__ __forceinline__ float lane_read(float v, int t) {
  return __int_as_float(__builtin_amdgcn_readlane(__float_as_int(v), t));
}
__device__ __forceinline__ short f2bf(float v) {
  __hip_bfloat16 h = __float2bfloat16(v);
  return *reinterpret_cast<short*>(&h);
}
// load 8 f32 (16B-aligned) -> bf16x8 fragment; zeroed when !valid
__device__ __forceinline__ short8 cvt8(const float* p, bool valid) {
  float4 u = *(const float4*)(p);
  float4 v = *(const float4*)(p + 4);
  short8 r;
  r[0] = f2bf(u.x); r[1] = f2bf(u.y); r[2] = f2bf(u.z); r[3] = f2bf(u.w);
  r[4] = f2bf(v.x); r[5] = f2bf(v.y); r[6] = f2bf(v.z); r[7] = f2bf(v.w);
  if (!valid) r = (short8)0;
  return r;
}

// ---------------------------------------------------------------------------
// LayerNorm (f32 out)
// ---------------------------------------------------------------------------
__global__ __launch_bounds__(256) void ln_kernel(const float* __restrict__ x,
                                                 const float* __restrict__ w,
                                                 const float* __restrict__ b,
                                                 float* __restrict__ h) {
  int l = blockIdx.x;
  int tid = threadIdx.x;
  const float* xr = x + l * DM;
  float s = 0.f, s2 = 0.f;
  for (int i = tid; i < DM; i += 256) { float t = xr[i]; s += t; s2 += t * t; }
#pragma unroll
  for (int off = 32; off; off >>= 1) { s += __shfl_xor(s, off); s2 += __shfl_xor(s2, off); }
  __shared__ float ls[4], ls2[4];
  int wid = tid >> 6, lane = tid & 63;
  if (lane == 0) { ls[wid] = s; ls2[wid] = s2; }
  __syncthreads();
  s = ls[0] + ls[1] + ls[2] + ls[3];
  s2 = ls2[0] + ls2[1] + ls2[2] + ls2[3];
  float mean = s * (1.f / DM);
  float var = s2 * (1.f / DM) - mean * mean;
  float rstd = rsqrtf(var + 1e-5f);
  for (int i = tid; i < DM; i += 256)
    h[l * DM + i] = (xr[i] - mean) * rstd * w[i] + b[i];
}

// ---------------------------------------------------------------------------
// bf16-MFMA GEMM, f32 operands converted in-register.
// C[M,N] = A[M,K] . B[N,K]^T, M=512. Block = 2 waves (128 thr); wave w covers
// n-cols [blockIdx.x*16, +16) x m-rows [blockIdx.y*64 + w*32, +32).
// Fragment math identical to the R4 kernel (verified):
//   A/B operand: lane holds [r=lane&15][k=(lane>>4)*8+j]
//   C/D:         col=lane&15, row=(lane>>4)*4+reg
// K handling: loop to Kpad (mult of 32); lanes with k>=K use a clamped
// address and a zeroed fragment (dt_proj: K=48, Kpad=64).
// mode: 0 = plain, 1 = softplus(v + bias[col]), 2 = v + res[m*N+col]
// ---------------------------------------------------------------------------
__global__ __launch_bounds__(128) void gemm_bf16(const float* __restrict__ A, int lda,
                                                 const float* __restrict__ B, int ldb,
                                                 float* __restrict__ C,
                                                 int N, int K, int Kpad,
                                                 const float* __restrict__ aux,
                                                 int mode) {
  int lane = threadIdx.x & 63;
  int w = threadIdx.x >> 6;
  int n0 = blockIdx.x * 16;
  int mbase = blockIdx.y * 64 + w * 32;
  int fr = lane & 15;
  int koff = (lane >> 4) * 8;
  const float* pB  = B + (size_t)(n0 + fr) * ldb;
  const float* pA0 = A + (size_t)(mbase + fr) * lda;
  const float* pA1 = pA0 + (size_t)16 * lda;
  float4v acc0 = (float4v){0.f, 0.f, 0.f, 0.f};
  float4v acc1 = (float4v){0.f, 0.f, 0.f, 0.f};
  for (int k0 = 0; k0 < Kpad; k0 += 32) {
    int kb = k0 + koff;
    bool valid = kb < K;
    int off = valid ? kb : 0;
    short8 bf = cvt8(pB + off, valid);
    short8 a0 = cvt8(pA0 + off, valid);
    short8 a1 = cvt8(pA1 + off, valid);
    acc0 = __builtin_amdgcn_mfma_f32_16x16x32_bf16(a0, bf, acc0, 0, 0, 0);
    acc1 = __builtin_amdgcn_mfma_f32_16x16x32_bf16(a1, bf, acc1, 0, 0, 0);
  }
  int col = n0 + fr;
  float bias = (mode == 1) ? aux[col] : 0.f;
#pragma unroll
  for (int mt = 0; mt < 2; ++mt) {
    float4v acc = mt ? acc1 : acc0;
#pragma unroll
    for (int r = 0; r < 4; ++r) {
      int m = mbase + mt * 16 + (lane >> 4) * 4 + r;
      float v = acc[r];
      if (mode == 1) {
        v += bias;
        v = (v > 20.f) ? v : log1pf(__expf(v));
      } else if (mode == 2) {
        v += aux[(size_t)m * N + col];
      }
      C[(size_t)m * N + col] = v;
    }
  }
}

// ---------------------------------------------------------------------------
// Causal depthwise conv (window 4) + bias + SiLU (f32)
// ---------------------------------------------------------------------------
__global__ __launch_bounds__(256) void conv_silu_kernel(const float* __restrict__ xz,
                                                        const float* __restrict__ cw,
                                                        const float* __restrict__ cb,
                                                        float* __restrict__ xc) {
  int idx = blockIdx.x * 256 + threadIdx.x;
  if (idx >= L_SEQ * DI) return;
  int l = idx / DI, d = idx - l * DI;
  float acc = cb[d];
#pragma unroll
  for (int j = 0; j < DC; ++j) {
    int ll = l - (DC - 1) + j;
    if (ll >= 0) acc = fmaf(xz[(size_t)ll * (2 * DI) + d], cw[d * DC + j], acc);
  }
  float sig = 1.f / (1.f + __expf(-acc));
  xc[idx] = acc * sig;
}

// ---------------------------------------------------------------------------
// Scan pass 1 (chunks 0..NC-2): local recurrence from 0; emit end state + sum(dt)
// ---------------------------------------------------------------------------
__global__ __launch_bounds__(256) void scan_p1(const float* __restrict__ dt,
                                               const float* __restrict__ xc,
                                               const float* __restrict__ xdbl,
                                               const float* __restrict__ A_log,
                                               float* __restrict__ send,
                                               float* __restrict__ dts) {
  int lane = threadIdx.x & 63;
  int wid = threadIdx.x >> 6;
  int pair = blockIdx.x * 4 + wid;
  int c = __builtin_amdgcn_readfirstlane(pair / DI);
  int d = __builtin_amdgcn_readfirstlane(pair - (pair / DI) * DI);
  float A = -__expf(A_log[(size_t)d * DS + lane]);
  int l0 = c * TC;
  float dtv = dt[(size_t)(l0 + lane) * DI + d];
  float xv  = xc[(size_t)(l0 + lane) * DI + d];
  const float* pB = xdbl + (size_t)l0 * NXD + DR + lane;
  float s = 0.f;
#pragma unroll 8
  for (int t = 0; t < TC; ++t) {
    float dt_c = lane_read(dtv, t);
    float x_c  = lane_read(xv, t);
    float B_c  = pB[(size_t)t * NXD];
    float dA = __expf(dt_c * A);
    s = fmaf(dA, s, dt_c * x_c * B_c);
  }
  float dsum = dtv;
  dsum = bp_add(dsum, (lane ^ 1) << 2);  dsum = bp_add(dsum, (lane ^ 2) << 2);
  dsum = bp_add(dsum, (lane ^ 4) << 2);  dsum = bp_add(dsum, (lane ^ 8) << 2);
  dsum = bp_add(dsum, (lane ^ 16) << 2); dsum = bp_add(dsum, (lane ^ 32) << 2);
  send[((size_t)c * DI + d) * DS + lane] = s;
  if (lane == 0) dts[c * DI + d] = dsum;
}

// ---------------------------------------------------------------------------
// Scan pass 2: prefix over chunks
// ---------------------------------------------------------------------------
__global__ __launch_bounds__(256) void scan_p2(const float* __restrict__ send,
                                               const float* __restrict__ dts,
                                               const float* __restrict__ A_log,
                                               float* __restrict__ sinit) {
  int lane = threadIdx.x & 63;
  int wid = threadIdx.x >> 6;
  int d = __builtin_amdgcn_readfirstlane(blockIdx.x * 4 + wid);
  float A = -__expf(A_log[(size_t)d * DS + lane]);
  float s = 0.f;
  for (int c = 1; c < NC; ++c) {
    float P = __expf(A * dts[(c - 1) * DI + d]);
    s = fmaf(P, s, send[((size_t)(c - 1) * DI + d) * DS + lane]);
    sinit[((size_t)c * DI + d) * DS + lane] = s;
  }
}

// ---------------------------------------------------------------------------
// Scan pass 3: recurrence from true init; n-reduction batched through LDS
// (16 steps of P=s*C in regs -> 16 ds_write + 8 ds_read_b64 + 3 bpermute).
// ---------------------------------------------------------------------------
__global__ __launch_bounds__(256) void scan_p3(const float* __restrict__ dt,
                                               const float* __restrict__ xc,
                                               const float* __restrict__ xdbl,
                                               const float* __restrict__ A_log,
                                               const float* __restrict__ Dv,
                                               const float* __restrict__ xz,
                                               const float* __restrict__ sinit,
                                               float* __restrict__ y) {
  __shared__ float Pb[4][16][66];
  int lane = threadIdx.x & 63;
  int wid = threadIdx.x >> 6;
  int pair = blockIdx.x * 4 + wid;
  int c = __builtin_amdgcn_readfirstlane(pair / DI);
  int d = __builtin_amdgcn_readfirstlane(pair - (pair / DI) * DI);
  float A = -__expf(A_log[(size_t)d * DS + lane]);
  float Dd = Dv[d];
  int l0 = c * TC;
  float dtv = dt[(size_t)(l0 + lane) * DI + d];
  float xv  = xc[(size_t)(l0 + lane) * DI + d];
  float zv  = xz[(size_t)(l0 + lane) * (2 * DI) + DI + d];
  float s = (c == 0) ? 0.f : sinit[((size_t)c * DI + d) * DS + lane];
  const float* pB = xdbl + (size_t)l0 * NXD + DR + lane;
  float yv = 0.f;
#pragma unroll
  for (int sb = 0; sb < 4; ++sb) {
    float P[16];
#pragma unroll
    for (int j = 0; j < 16; ++j) {
      int t = sb * 16 + j;
      float dt_c = lane_read(dtv, t);
      float x_c  = lane_read(xv, t);
      float B_c  = pB[(size_t)t * NXD];
      float C_c  = pB[(size_t)t * NXD + DS];
      float dA = __expf(dt_c * A);
      s = fmaf(dA, s, dt_c * x_c * B_c);
      P[j] = s * C_c;
    }
#pragma unroll
    for (int j = 0; j < 16; ++j) Pb[wid][j][lane] = P[j];
    int t4 = lane >> 2, q = lane & 3;
    const float* row = &Pb[wid][t4][q * 16];
    float part = 0.f;
#pragma unroll
    for (int k = 0; k < 8; ++k) {
      float2 v2 = *(const float2*)(row + 2 * k);
      part += v2.x + v2.y;
    }
    part = bp_add(part, (lane ^ 1) << 2);
    part = bp_add(part, (lane ^ 2) << 2);
    float got = __int_as_float(
        __builtin_amdgcn_ds_bpermute((lane & 15) << 4, __float_as_int(part)));
    yv = ((lane >> 4) == sb) ? got : yv;
  }
  float sig = 1.f / (1.f + __expf(-zv));
  y[(size_t)(l0 + lane) * DI + d] = (yv + xv * Dd) * (zv * sig);
}

// ---------------------------------------------------------------------------
// Launcher (9 dispatches, all f32 buffers)
// ---------------------------------------------------------------------------
extern "C" void kernel_launch(void* const* d_in, const int* in_sizes, int n_in,
                              void* d_out, int out_size, void* d_ws, size_t ws_size,
                              hipStream_t stream) {
  const float* x         = (const float*)d_in[0];
  const float* ln_w      = (const float*)d_in[1];
  const float* ln_b      = (const float*)d_in[2];
  const float* in_proj_w = (const float*)d_in[3];
  const float* conv_w    = (const float*)d_in[4];
  const float* conv_b    = (const float*)d_in[5];
  const float* x_proj_w  = (const float*)d_in[6];
  const float* dt_proj_w = (const float*)d_in[7];
  const float* dt_proj_b = (const float*)d_in[8];
  const float* A_log     = (const float*)d_in[9];
  const float* Dv        = (const float*)d_in[10];
  const float* out_proj_w= (const float*)d_in[11];
  float* out = (float*)d_out;

  float* ws = (float*)d_ws;
  float* h     = ws;                        // 512*768   = 393216
  float* xz    = h + 393216;                // 512*3072  = 1572864
  float* xconv = xz + 1572864;              // 786432
  float* xdbl  = xconv + 786432;            // 90112
  float* dtb   = xdbl + 90112;              // 786432
  float* send  = dtb + 786432;              // 688128
  float* dts   = send + 688128;             // 10752
  float* sinit = dts + 10752;               // 786432
  float* yb    = sinit + 786432;            // 786432

  // 1. LayerNorm
  ln_kernel<<<L_SEQ, 256, 0, stream>>>(x, ln_w, ln_b, h);

  // 2. in_proj: xz[512,3072] = h . Wi^T   (grid 192x8 = 1536 blocks)
  gemm_bf16<<<dim3(2 * DI / 16, L_SEQ / 64), 128, 0, stream>>>(
      h, DM, in_proj_w, DM, xz, 2 * DI, DM, DM, nullptr, 0);

  // 3. conv + SiLU
  conv_silu_kernel<<<(L_SEQ * DI) / 256, 256, 0, stream>>>(xz, conv_w, conv_b, xconv);

  // 4. x_proj: xdbl[512,176] = xconv . Wx^T  (grid 11x8)
  gemm_bf16<<<dim3(NXD / 16, L_SEQ / 64), 128, 0, stream>>>(
      xconv, DI, x_proj_w, DI, xdbl, NXD, DI, DI, nullptr, 0);

  // 5. dt_proj: dtb[512,1536] = softplus(xdbl[:, :48] . Wdt^T + b)  (grid 96x8)
  gemm_bf16<<<dim3(DI / 16, L_SEQ / 64), 128, 0, stream>>>(
      xdbl, NXD, dt_proj_w, DR, dtb, DI, DR, 64, dt_proj_b, 1);

  // 6. chunked selective scan
  scan_p1<<<((NC - 1) * DI) / 4, 256, 0, stream>>>(dtb, xconv, xdbl, A_log, send, dts);
  scan_p2<<<DI / 4, 256, 0, stream>>>(send, dts, A_log, sinit);
  scan_p3<<<(NC * DI) / 4, 256, 0, stream>>>(dtb, xconv, xdbl, A_log, Dv, xz, sinit, yb);

  // 7. out_proj + residual: out = x + yb . Wo^T  (grid 48x8)
  gemm_bf16<<<dim3(DM / 16, L_SEQ / 64), 128, 0, stream>>>(
      yb, DI, out_proj_w, DI, out, DM, DI, DI, x, 2);
}

// Round 6
// 208.932 us; speedup vs baseline: 1.2934x; 1.2934x over previous
//
#include <hip/hip_runtime.h>
#include <hip/hip_bf16.h>
#include <math.h>

#define L_SEQ 512
#define DM 768
#define DI 1536
#define DS 64
#define DC 4
#define DR 48
#define NXD 176  // DR + 2*DS
#define NC 8     // time chunks
#define TC 64    // steps per chunk

typedef __attribute__((ext_vector_type(8))) short short8;
typedef __attribute__((ext_vector_type(4))) float float4v;

// sizes (elements)
#define NWI (2 * DI * DM)   // 2359296
#define NWX (NXD * DI)      // 270336
#define NWDT (DI * DR)      // 73728
#define NWO (DM * DI)       // 1179648
#define NXZ (L_SEQ * 2 * DI)  // 1572864
#define NXDBL (L_SEQ * NXD)   // 90112
#define NXR (L_SEQ * DM)      // 393216

// prep grid partition (1024 elems per cvt/zero/copy block)
#define B_LN 512
#define B_WI (NWI / 1024)     // 2304
#define B_WX (NWX / 1024)     // 264
#define B_WDT (NWDT / 1024)   // 72
#define B_WO (NWO / 1024)     // 1152
#define B_XZ (NXZ / 1024)     // 1536
#define B_XD (NXDBL / 1024)   // 88
#define B_CP (NXR / 1024)     // 384
#define PREP_GRID (B_LN + B_WI + B_WX + B_WDT + B_WO + B_XZ + B_XD + B_CP)

// ---------------------------------------------------------------------------
// helpers
// ---------------------------------------------------------------------------
__device__ __forceinline__ float bp_add(float p, int addr) {
  return p + __int_as_float(__builtin_amdgcn_ds_bpermute(addr, __float_as_int(p)));
}
__device__ __forceinline__ float lane_read(float v, int t) {
  return __int_as_float(__builtin_amdgcn_readlane(__float_as_int(v), t));
}
__device__ __forceinline__ short f2bf(float v) {
  __hip_bfloat16 h = __float2bfloat16(v);
  return *reinterpret_cast<short*>(&h);
}
__device__ __forceinline__ short8 cvt8f(const float* p, bool valid) {
  float4 u = *(const float4*)(p);
  float4 v = *(const float4*)(p + 4);
  short8 r;
  r[0] = f2bf(u.x); r[1] = f2bf(u.y); r[2] = f2bf(u.z); r[3] = f2bf(u.w);
  r[4] = f2bf(v.x); r[5] = f2bf(v.y); r[6] = f2bf(v.z); r[7] = f2bf(v.w);
  if (!valid) r = (short8)0;
  return r;
}
__device__ __forceinline__ void atomic_addf(float* p, float v) {
  __hip_atomic_fetch_add(p, v, __ATOMIC_RELAXED, __HIP_MEMORY_SCOPE_AGENT);
}

// ---------------------------------------------------------------------------
// prep: LN (blocks 0..511) + weight cvts + zero xz/xdbl + copy x->out.
// Each job is block-uniform (branch on blockIdx only).
// ---------------------------------------------------------------------------
__device__ __forceinline__ void cvt_blk(const float* __restrict__ s,
                                        short* __restrict__ d, int b) {
  int i = b * 1024 + threadIdx.x * 4;
  float4 v = *(const float4*)(s + i);
  short4 o; o.x = f2bf(v.x); o.y = f2bf(v.y); o.z = f2bf(v.z); o.w = f2bf(v.w);
  *(short4*)(d + i) = o;
}
__global__ __launch_bounds__(256) void prep(
    const float* __restrict__ x, const float* __restrict__ lnw,
    const float* __restrict__ lnb, short* __restrict__ h,
    const float* __restrict__ wi, short* __restrict__ wib,
    const float* __restrict__ wx, short* __restrict__ wxb,
    const float* __restrict__ wdt, short* __restrict__ wdtb,
    const float* __restrict__ wo, short* __restrict__ wob,
    float* __restrict__ xz, float* __restrict__ xdbl, float* __restrict__ out) {
  int b = blockIdx.x;
  if (b < B_LN) {  // LayerNorm row b -> bf16 h
    int l = b, tid = threadIdx.x;
    const float* xr = x + l * DM;
    float s = 0.f, s2 = 0.f;
    for (int i = tid; i < DM; i += 256) { float t = xr[i]; s += t; s2 += t * t; }
#pragma unroll
    for (int off = 32; off; off >>= 1) { s += __shfl_xor(s, off); s2 += __shfl_xor(s2, off); }
    __shared__ float ls[4], ls2[4];
    int wid = tid >> 6, lane = tid & 63;
    if (lane == 0) { ls[wid] = s; ls2[wid] = s2; }
    __syncthreads();
    s = ls[0] + ls[1] + ls[2] + ls[3];
    s2 = ls2[0] + ls2[1] + ls2[2] + ls2[3];
    float mean = s * (1.f / DM);
    float var = s2 * (1.f / DM) - mean * mean;
    float rstd = rsqrtf(var + 1e-5f);
    for (int i = tid; i < DM; i += 256)
      h[l * DM + i] = f2bf((xr[i] - mean) * rstd * lnw[i] + lnb[i]);
    return;
  }
  b -= B_LN;
  if (b < B_WI) { cvt_blk(wi, wib, b); return; }
  b -= B_WI;
  if (b < B_WX) { cvt_blk(wx, wxb, b); return; }
  b -= B_WX;
  if (b < B_WDT) { cvt_blk(wdt, wdtb, b); return; }
  b -= B_WDT;
  if (b < B_WO) { cvt_blk(wo, wob, b); return; }
  b -= B_WO;
  if (b < B_XZ) {
    int i = b * 1024 + threadIdx.x * 4;
    *(float4*)(xz + i) = make_float4(0.f, 0.f, 0.f, 0.f);
    return;
  }
  b -= B_XZ;
  if (b < B_XD) {
    int i = b * 1024 + threadIdx.x * 4;
    *(float4*)(xdbl + i) = make_float4(0.f, 0.f, 0.f, 0.f);
    return;
  }
  b -= B_XD;
  {
    int i = b * 1024 + threadIdx.x * 4;
    *(float4*)(out + i) = *(const float4*)(x + i);
  }
}

// ---------------------------------------------------------------------------
// bf16-MFMA GEMM with split-K + f32 atomic accumulation.
// C[M,N] += A[M,K].B[N,K]^T over this block's K-slice. C must be pre-inited
// (zero, or residual for out_proj). Block = 4 waves; wave w owns the
// (w&1)-th 32m x (w>>1)-th 32n quadrant of a 64x64 tile: 2 A-frags +
// 2 B-frags + 4 MFMA per 32-K chunk, depth-1 software prefetch.
// Fragment math (verified R4): operand lane holds [r=lane&15][k=(lane>>4)*8+j];
// C/D col=lane&15, row=(lane>>4)*4+reg.
// ---------------------------------------------------------------------------
__global__ __launch_bounds__(256) void gemm_bf16(const short* __restrict__ A, int lda,
                                                 const short* __restrict__ B,
                                                 float* __restrict__ C,
                                                 int N, int K) {
  int lane = threadIdx.x & 63, w = threadIdx.x >> 6;
  int fr = lane & 15, koff = (lane >> 4) * 8;
  int mbase = blockIdx.y * 64 + (w & 1) * 32;
  int nbase = blockIdx.x * 64 + (w >> 1) * 32;
  int kchunk = K / gridDim.z;
  int kbeg = blockIdx.z * kchunk, kend = kbeg + kchunk;
  int nr0 = nbase + fr;      if (nr0 > N - 1) nr0 = N - 1;
  int nr1 = nbase + 16 + fr; if (nr1 > N - 1) nr1 = N - 1;
  const short* pA0 = A + (size_t)(mbase + fr) * lda + koff;
  const short* pA1 = pA0 + (size_t)16 * lda;
  const short* pB0 = B + (size_t)nr0 * K + koff;
  const short* pB1 = B + (size_t)nr1 * K + koff;
  float4v acc00 = (float4v){0.f,0.f,0.f,0.f}, acc01 = acc00;
  float4v acc10 = acc00, acc11 = acc00;
  short8 a0 = *(const short8*)(pA0 + kbeg);
  short8 a1 = *(const short8*)(pA1 + kbeg);
  short8 b0 = *(const short8*)(pB0 + kbeg);
  short8 b1 = *(const short8*)(pB1 + kbeg);
  for (int k0 = kbeg; k0 < kend; k0 += 32) {
    short8 ca0 = a0, ca1 = a1, cb0 = b0, cb1 = b1;
    int kn = (k0 + 32 < kend) ? k0 + 32 : kbeg;  // safe addr for last iter
    a0 = *(const short8*)(pA0 + kn);
    a1 = *(const short8*)(pA1 + kn);
    b0 = *(const short8*)(pB0 + kn);
    b1 = *(const short8*)(pB1 + kn);
    acc00 = __builtin_amdgcn_mfma_f32_16x16x32_bf16(ca0, cb0, acc00, 0, 0, 0);
    acc01 = __builtin_amdgcn_mfma_f32_16x16x32_bf16(ca0, cb1, acc01, 0, 0, 0);
    acc10 = __builtin_amdgcn_mfma_f32_16x16x32_bf16(ca1, cb0, acc10, 0, 0, 0);
    acc11 = __builtin_amdgcn_mfma_f32_16x16x32_bf16(ca1, cb1, acc11, 0, 0, 0);
  }
  int col0 = nbase + fr, col1 = nbase + 16 + fr;
  int rb = mbase + (lane >> 4) * 4;
#pragma unroll
  for (int r = 0; r < 4; ++r) {
    if (col0 < N) {
      atomic_addf(&C[(size_t)(rb + r) * N + col0], acc00[r]);
      atomic_addf(&C[(size_t)(rb + 16 + r) * N + col0], acc10[r]);
    }
    if (col1 < N) {
      atomic_addf(&C[(size_t)(rb + r) * N + col1], acc01[r]);
      atomic_addf(&C[(size_t)(rb + 16 + r) * N + col1], acc11[r]);
    }
  }
}

// ---------------------------------------------------------------------------
// dt_proj: dt[512,DI] = softplus(xdbl[:, :48] . Wdt^T + bias). K=48 pad 64,
// A is f32 (post-atomic xdbl) cvt'd in-reg (only 2 chunks - cost nil),
// B is bf16 (pre-converted). Same wave mapping as gemm_bf16, grid (DI/64, 8).
// ---------------------------------------------------------------------------
__global__ __launch_bounds__(256) void dtp_gemm(const float* __restrict__ Axd,
                                                const short* __restrict__ Bw,
                                                float* __restrict__ dt,
                                                const float* __restrict__ bias) {
  int lane = threadIdx.x & 63, w = threadIdx.x >> 6;
  int fr = lane & 15, koff = (lane >> 4) * 8;
  int mbase = blockIdx.y * 64 + (w & 1) * 32;
  int nbase = blockIdx.x * 64 + (w >> 1) * 32;
  const float* pA0 = Axd + (size_t)(mbase + fr) * NXD;
  const float* pA1 = pA0 + (size_t)16 * NXD;
  const short* pB0 = Bw + (size_t)(nbase + fr) * DR;
  const short* pB1 = Bw + (size_t)(nbase + 16 + fr) * DR;
  float4v acc00 = (float4v){0.f,0.f,0.f,0.f}, acc01 = acc00;
  float4v acc10 = acc00, acc11 = acc00;
#pragma unroll
  for (int k0 = 0; k0 < 64; k0 += 32) {
    bool valid = (k0 + koff) < DR;
    int off = valid ? k0 + koff : 0;
    short8 a0 = cvt8f(pA0 + off, valid);
    short8 a1 = cvt8f(pA1 + off, valid);
    short8 b0 = *(const short8*)(pB0 + off);
    short8 b1 = *(const short8*)(pB1 + off);
    if (!valid) { b0 = (short8)0; b1 = (short8)0; }
    acc00 = __builtin_amdgcn_mfma_f32_16x16x32_bf16(a0, b0, acc00, 0, 0, 0);
    acc01 = __builtin_amdgcn_mfma_f32_16x16x32_bf16(a0, b1, acc01, 0, 0, 0);
    acc10 = __builtin_amdgcn_mfma_f32_16x16x32_bf16(a1, b0, acc10, 0, 0, 0);
    acc11 = __builtin_amdgcn_mfma_f32_16x16x32_bf16(a1, b1, acc11, 0, 0, 0);
  }
  int col0 = nbase + fr, col1 = nbase + 16 + fr;
  float bi0 = bias[col0], bi1 = bias[col1];
  int rb = mbase + (lane >> 4) * 4;
#pragma unroll
  for (int r = 0; r < 4; ++r) {
    float v0 = acc00[r] + bi0, v1 = acc01[r] + bi1;
    float v2 = acc10[r] + bi0, v3 = acc11[r] + bi1;
    v0 = (v0 > 20.f) ? v0 : log1pf(__expf(v0));
    v1 = (v1 > 20.f) ? v1 : log1pf(__expf(v1));
    v2 = (v2 > 20.f) ? v2 : log1pf(__expf(v2));
    v3 = (v3 > 20.f) ? v3 : log1pf(__expf(v3));
    dt[(size_t)(rb + r) * DI + col0] = v0;
    dt[(size_t)(rb + r) * DI + col1] = v1;
    dt[(size_t)(rb + 16 + r) * DI + col0] = v2;
    dt[(size_t)(rb + 16 + r) * DI + col1] = v3;
  }
}

// ---------------------------------------------------------------------------
// Causal depthwise conv (window 4) + bias + SiLU; dual store f32 + bf16
// ---------------------------------------------------------------------------
__global__ __launch_bounds__(256) void conv_silu_kernel(const float* __restrict__ xz,
                                                        const float* __restrict__ cw,
                                                        const float* __restrict__ cb,
                                                        float* __restrict__ xc,
                                                        short* __restrict__ xcb) {
  int idx = blockIdx.x * 256 + threadIdx.x;
  if (idx >= L_SEQ * DI) return;
  int l = idx / DI, d = idx - l * DI;
  float acc = cb[d];
#pragma unroll
  for (int j = 0; j < DC; ++j) {
    int ll = l - (DC - 1) + j;
    if (ll >= 0) acc = fmaf(xz[(size_t)ll * (2 * DI) + d], cw[d * DC + j], acc);
  }
  float sig = 1.f / (1.f + __expf(-acc));
  float v = acc * sig;
  xc[idx] = v;
  xcb[idx] = f2bf(v);
}

// ---------------------------------------------------------------------------
// Scan pass 1 (chunks 0..NC-2): local recurrence from 0; emit end state + sum(dt)
// ---------------------------------------------------------------------------
__global__ __launch_bounds__(256) void scan_p1(const float* __restrict__ dt,
                                               const float* __restrict__ xc,
                                               const float* __restrict__ xdbl,
                                               const float* __restrict__ A_log,
                                               float* __restrict__ send,
                                               float* __restrict__ dts) {
  int lane = threadIdx.x & 63;
  int wid = threadIdx.x >> 6;
  int pair = blockIdx.x * 4 + wid;
  int c = __builtin_amdgcn_readfirstlane(pair / DI);
  int d = __builtin_amdgcn_readfirstlane(pair - (pair / DI) * DI);
  float A = -__expf(A_log[(size_t)d * DS + lane]);
  int l0 = c * TC;
  float dtv = dt[(size_t)(l0 + lane) * DI + d];
  float xv  = xc[(size_t)(l0 + lane) * DI + d];
  const float* pB = xdbl + (size_t)l0 * NXD + DR + lane;
  float s = 0.f;
#pragma unroll 8
  for (int t = 0; t < TC; ++t) {
    float dt_c = lane_read(dtv, t);
    float x_c  = lane_read(xv, t);
    float B_c  = pB[(size_t)t * NXD];
    float dA = __expf(dt_c * A);
    s = fmaf(dA, s, dt_c * x_c * B_c);
  }
  float dsum = dtv;
  dsum = bp_add(dsum, (lane ^ 1) << 2);  dsum = bp_add(dsum, (lane ^ 2) << 2);
  dsum = bp_add(dsum, (lane ^ 4) << 2);  dsum = bp_add(dsum, (lane ^ 8) << 2);
  dsum = bp_add(dsum, (lane ^ 16) << 2); dsum = bp_add(dsum, (lane ^ 32) << 2);
  send[((size_t)c * DI + d) * DS + lane] = s;
  if (lane == 0) dts[c * DI + d] = dsum;
}

// ---------------------------------------------------------------------------
// Scan pass 2: prefix over chunks
// ---------------------------------------------------------------------------
__global__ __launch_bounds__(256) void scan_p2(const float* __restrict__ send,
                                               const float* __restrict__ dts,
                                               const float* __restrict__ A_log,
                                               float* __restrict__ sinit) {
  int lane = threadIdx.x & 63;
  int wid = threadIdx.x >> 6;
  int d = __builtin_amdgcn_readfirstlane(blockIdx.x * 4 + wid);
  float A = -__expf(A_log[(size_t)d * DS + lane]);
  float s = 0.f;
  for (int c = 1; c < NC; ++c) {
    float P = __expf(A * dts[(c - 1) * DI + d]);
    s = fmaf(P, s, send[((size_t)(c - 1) * DI + d) * DS + lane]);
    sinit[((size_t)c * DI + d) * DS + lane] = s;
  }
}

// ---------------------------------------------------------------------------
// Scan pass 3: recurrence from true init; LDS-batched n-reduction; bf16 y out.
// ---------------------------------------------------------------------------
__global__ __launch_bounds__(256) void scan_p3(const float* __restrict__ dt,
                                               const float* __restrict__ xc,
                                               const float* __restrict__ xdbl,
                                               const float* __restrict__ A_log,
                                               const float* __restrict__ Dv,
                                               const float* __restrict__ xz,
                                               const float* __restrict__ sinit,
                                               short* __restrict__ y) {
  __shared__ float Pb[4][16][66];
  int lane = threadIdx.x & 63;
  int wid = threadIdx.x >> 6;
  int pair = blockIdx.x * 4 + wid;
  int c = __builtin_amdgcn_readfirstlane(pair / DI);
  int d = __builtin_amdgcn_readfirstlane(pair - (pair / DI) * DI);
  float A = -__expf(A_log[(size_t)d * DS + lane]);
  float Dd = Dv[d];
  int l0 = c * TC;
  float dtv = dt[(size_t)(l0 + lane) * DI + d];
  float xv  = xc[(size_t)(l0 + lane) * DI + d];
  float zv  = xz[(size_t)(l0 + lane) * (2 * DI) + DI + d];
  float s = (c == 0) ? 0.f : sinit[((size_t)c * DI + d) * DS + lane];
  const float* pB = xdbl + (size_t)l0 * NXD + DR + lane;
  float yv = 0.f;
#pragma unroll
  for (int sb = 0; sb < 4; ++sb) {
    float P[16];
#pragma unroll
    for (int j = 0; j < 16; ++j) {
      int t = sb * 16 + j;
      float dt_c = lane_read(dtv, t);
      float x_c  = lane_read(xv, t);
      float B_c  = pB[(size_t)t * NXD];
      float C_c  = pB[(size_t)t * NXD + DS];
      float dA = __expf(dt_c * A);
      s = fmaf(dA, s, dt_c * x_c * B_c);
      P[j] = s * C_c;
    }
#pragma unroll
    for (int j = 0; j < 16; ++j) Pb[wid][j][lane] = P[j];
    int t4 = lane >> 2, q = lane & 3;
    const float* row = &Pb[wid][t4][q * 16];
    float part = 0.f;
#pragma unroll
    for (int k = 0; k < 8; ++k) {
      float2 v2 = *(const float2*)(row + 2 * k);
      part += v2.x + v2.y;
    }
    part = bp_add(part, (lane ^ 1) << 2);
    part = bp_add(part, (lane ^ 2) << 2);
    float got = __int_as_float(
        __builtin_amdgcn_ds_bpermute((lane & 15) << 4, __float_as_int(part)));
    yv = ((lane >> 4) == sb) ? got : yv;
  }
  float sig = 1.f / (1.f + __expf(-zv));
  y[(size_t)(l0 + lane) * DI + d] = f2bf((yv + xv * Dd) * (zv * sig));
}

// ---------------------------------------------------------------------------
// Launcher (9 dispatches)
// ---------------------------------------------------------------------------
extern "C" void kernel_launch(void* const* d_in, const int* in_sizes, int n_in,
                              void* d_out, int out_size, void* d_ws, size_t ws_size,
                              hipStream_t stream) {
  const float* x         = (const float*)d_in[0];
  const float* ln_w      = (const float*)d_in[1];
  const float* ln_b      = (const float*)d_in[2];
  const float* in_proj_w = (const float*)d_in[3];
  const float* conv_w    = (const float*)d_in[4];
  const float* conv_b    = (const float*)d_in[5];
  const float* x_proj_w  = (const float*)d_in[6];
  const float* dt_proj_w = (const float*)d_in[7];
  const float* dt_proj_b = (const float*)d_in[8];
  const float* A_log     = (const float*)d_in[9];
  const float* Dv        = (const float*)d_in[10];
  const float* out_proj_w= (const float*)d_in[11];
  float* out = (float*)d_out;

  float* ws = (float*)d_ws;
  // f32 region
  float* xz    = ws;                        // 1572864
  float* xconv = xz + NXZ;                  // 786432
  float* xdbl  = xconv + 786432;            // 90112
  float* dtb   = xdbl + NXDBL;              // 786432
  float* send  = dtb + 786432;              // 688128
  float* dts   = send + 688128;             // 10752
  float* sinit = dts + 10752;               // 786432
  float* fend  = sinit + 786432;
  // bf16 region
  short* h_bf   = (short*)fend;             // 393216
  short* wi_bf  = h_bf + NXR;               // 2359296
  short* wx_bf  = wi_bf + NWI;              // 270336
  short* wdt_bf = wx_bf + NWX;              // 73728
  short* wo_bf  = wdt_bf + NWDT;            // 1179648
  short* xc_bf  = wo_bf + NWO;              // 786432
  short* y_bf   = xc_bf + (L_SEQ * DI);     // 786432

  // 1. prep: LN + weight cvts + zero xz/xdbl + copy x->out
  prep<<<PREP_GRID, 256, 0, stream>>>(x, ln_w, ln_b, h_bf,
                                      in_proj_w, wi_bf, x_proj_w, wx_bf,
                                      dt_proj_w, wdt_bf, out_proj_w, wo_bf,
                                      xz, xdbl, out);

  // 2. in_proj: xz += h . Wi^T   (split-K 3; grid 48x8x3)
  gemm_bf16<<<dim3(2 * DI / 64, L_SEQ / 64, 3), 256, 0, stream>>>(
      h_bf, DM, wi_bf, xz, 2 * DI, DM);

  // 3. conv + SiLU (f32 + bf16)
  conv_silu_kernel<<<(L_SEQ * DI) / 256, 256, 0, stream>>>(xz, conv_w, conv_b,
                                                           xconv, xc_bf);

  // 4. x_proj: xdbl += xconv . Wx^T  (split-K 16; grid 3x8x16)
  gemm_bf16<<<dim3((NXD + 63) / 64, L_SEQ / 64, 16), 256, 0, stream>>>(
      xc_bf, DI, wx_bf, xdbl, NXD, DI);

  // 5. dt_proj + softplus (grid 24x8)
  dtp_gemm<<<dim3(DI / 64, L_SEQ / 64), 256, 0, stream>>>(
      xdbl, wdt_bf, dtb, dt_proj_b);

  // 6. chunked selective scan
  scan_p1<<<((NC - 1) * DI) / 4, 256, 0, stream>>>(dtb, xconv, xdbl, A_log, send, dts);
  scan_p2<<<DI / 4, 256, 0, stream>>>(send, dts, A_log, sinit);
  scan_p3<<<(NC * DI) / 4, 256, 0, stream>>>(dtb, xconv, xdbl, A_log, Dv, xz, sinit, y_bf);

  // 7. out_proj: out(=x) += y . Wo^T  (split-K 6; grid 12x8x6)
  gemm_bf16<<<dim3(DM / 64, L_SEQ / 64, 6), 256, 0, stream>>>(
      y_bf, DI, wo_bf, out, DM, DI);
}